// Round 1
// 899.634 us; speedup vs baseline: 1.1904x; 1.1904x over previous
//
#include <hip/hip_runtime.h>
#include <float.h>

// GenerativeUpsample BCE get_keep + prune.
// Inputs: fea (N,64) f32, pred_f (N,1) f32, batch_ids (N,) i32 sorted,
//         target_points_num (8,) i32.
// Outputs (concat): pruned_fea (N*64) f32, keep (N,) written as 0/1 f32.
//
// Exact per-batch kth-smallest via 4-pass 8-bit MSD radix select on the
// monotonic uint transform of the float bits, then one memory-bound prune pass.
//
// R1 changes vs previous (1070 us):
//  - scan kernels: serial 256-iter data-dependent-break loop (latency-bound,
//    ~25-90 us each with GPU idle) -> 8 blocks x 256 threads, one thread per
//    bin, LDS Hillis-Steele inclusive scan + winner-thread select (~5 us).
//  - histN: LDS-privatized histograms + active/prefix cached in LDS
//    (pass 1 did ~1M global atomics before), grid-stride 2048 blocks.
//  - prune: grid-stride 8192 blocks instead of 131072 tiny blocks
//    (block-dispatch overhead), thresh cached in LDS.

#define BATCHES 8

__device__ __forceinline__ unsigned f2key(float x) {
    unsigned u = __float_as_uint(x);
    return (u & 0x80000000u) ? ~u : (u | 0x80000000u);
}
__device__ __forceinline__ float key2f(unsigned k) {
    unsigned u = (k & 0x80000000u) ? (k & 0x7FFFFFFFu) : ~k;
    return __uint_as_float(u);
}

// Workspace layout (uint32 units)
static constexpr int HIST_OFF   = 0;      // 4 passes x 8 batches x 256 bins
static constexpr int REMK_OFF   = 8192;   // 8  remaining rank per batch
static constexpr int PREFIX_OFF = 8200;   // 8  accumulated key prefix
static constexpr int ACTIVE_OFF = 8208;   // 8
static constexpr int THRESH_OFF = 8216;   // 8  (float)
static constexpr int WS_INTS    = 8224;

// ---- Pass 0 histogram (all elements, LDS hist)
__global__ __launch_bounds__(256) void hist0_kernel(const float* __restrict__ pred,
                                                    const int* __restrict__ bids,
                                                    unsigned* __restrict__ hist,
                                                    int n) {
    __shared__ unsigned lh[BATCHES * 256];
    for (int i = threadIdx.x; i < BATCHES * 256; i += blockDim.x) lh[i] = 0u;
    __syncthreads();
    int stride = gridDim.x * blockDim.x;
    for (int i = blockIdx.x * blockDim.x + threadIdx.x; i < n; i += stride) {
        int b = bids[i];
        unsigned key = f2key(pred[i]);
        atomicAdd(&lh[b * 256 + (key >> 24)], 1u);
    }
    __syncthreads();
    for (int i = threadIdx.x; i < BATCHES * 256; i += blockDim.x) {
        unsigned v = lh[i];
        if (v) atomicAdd(&hist[i], v);
    }
}

// ---- Passes 1..3 histogram: only prefix-matching elements, LDS-privatized
__global__ __launch_bounds__(256) void histN_kernel(const float* __restrict__ pred,
                                                    const int* __restrict__ bids,
                                                    const unsigned* __restrict__ prefix,
                                                    const unsigned* __restrict__ active,
                                                    unsigned* __restrict__ hist,
                                                    int n, int shiftHi, int shiftBin) {
    __shared__ unsigned lh[BATCHES * 256];
    __shared__ unsigned lpre[BATCHES];
    __shared__ unsigned lact[BATCHES];
    for (int i = threadIdx.x; i < BATCHES * 256; i += blockDim.x) lh[i] = 0u;
    if (threadIdx.x < BATCHES) {
        lpre[threadIdx.x] = prefix[threadIdx.x];
        lact[threadIdx.x] = active[threadIdx.x];
    }
    __syncthreads();
    int stride = gridDim.x * blockDim.x;
    for (int i = blockIdx.x * blockDim.x + threadIdx.x; i < n; i += stride) {
        int b = bids[i];
        if (!lact[b]) continue;
        unsigned key = f2key(pred[i]);
        if ((key >> shiftHi) == lpre[b])
            atomicAdd(&lh[b * 256 + ((key >> shiftBin) & 0xFFu)], 1u);
    }
    __syncthreads();
    for (int i = threadIdx.x; i < BATCHES * 256; i += blockDim.x) {
        unsigned v = lh[i];
        if (v) atomicAdd(&hist[i], v);
    }
}

// ---- Parallel scan/select: 8 blocks (one per batch) x 256 threads (one per bin).
// LDS Hillis-Steele inclusive prefix sum over bins, then the unique thread whose
// bin interval [excl, incl) contains the rank writes prefix/remk (and thresh on
// the final pass). Replaces the serial data-dependent-break loop that left the
// GPU latency-bound for ~25-90 us per scan.
__global__ __launch_bounds__(256) void scan_kernel(const unsigned* __restrict__ hist,
                                                   const int* __restrict__ target,
                                                   unsigned* __restrict__ remk,
                                                   unsigned* __restrict__ prefix,
                                                   unsigned* __restrict__ active,
                                                   float* __restrict__ thresh,
                                                   int pass) {
    int b = blockIdx.x;
    int t = threadIdx.x;
    if (pass > 0 && !active[b]) {
        if (pass == 3 && t == 0) thresh[b] = -FLT_MAX;
        return;
    }
    __shared__ unsigned s[256];
    const unsigned* h = hist + (pass * BATCHES + b) * 256;
    unsigned c = h[t];
    s[t] = c;
    __syncthreads();
    // Hillis-Steele inclusive scan over 256 bins (8 steps)
    for (int off = 1; off < 256; off <<= 1) {
        unsigned v = s[t];
        unsigned a = (t >= off) ? s[t - off] : 0u;
        __syncthreads();
        s[t] = v + a;
        __syncthreads();
    }
    unsigned incl = s[t];
    unsigned total = s[255];
    unsigned r;
    if (pass == 0) {
        int tg = target[b];
        bool act = ((int)total > tg) && (total > 0u);
        if (t == 0) active[b] = act ? 1u : 0u;
        if (!act) return;   // uniform across block
        r = total - (unsigned)tg - 1u;  // 0-indexed rank of kth smallest
    } else {
        r = remk[b];
    }
    __syncthreads();  // all reads of remk[b] complete before the winner writes
    unsigned excl = incl - c;
    if (c > 0u && excl <= r && r < incl) {
        unsigned p = (pass == 0) ? (unsigned)t : ((prefix[b] << 8) | (unsigned)t);
        prefix[b] = p;
        remk[b] = r - excl;
        if (pass == 3) thresh[b] = key2f(p);
    }
}

// ---- Prune: one thread per float4 (16 threads per row of 64 floats), grid-stride
__global__ __launch_bounds__(256) void prune_kernel(const float* __restrict__ fea,
                                                    const float* __restrict__ pred,
                                                    const int* __restrict__ bids,
                                                    const float* __restrict__ thresh,
                                                    float* __restrict__ out,
                                                    int n) {
    __shared__ float sth[BATCHES];
    if (threadIdx.x < BATCHES) sth[threadIdx.x] = thresh[threadIdx.x];
    __syncthreads();
    long total4 = (long)n * 16;
    long stride = (long)gridDim.x * blockDim.x;
    for (long idx = (long)blockIdx.x * blockDim.x + threadIdx.x; idx < total4;
         idx += stride) {
        int row = (int)(idx >> 4);
        int l = (int)(idx & 15);
        int b = bids[row];
        bool kp = pred[row] > sth[b];
        float4* dst = (float4*)out + idx;
        if (kp) {
            *dst = ((const float4*)fea)[idx];
        } else {
            *dst = make_float4(0.f, 0.f, 0.f, 0.f);
        }
        if (l == 0) out[(size_t)n * 64 + row] = kp ? 1.0f : 0.0f;
    }
}

extern "C" void kernel_launch(void* const* d_in, const int* in_sizes, int n_in,
                              void* d_out, int out_size, void* d_ws, size_t ws_size,
                              hipStream_t stream) {
    const float* fea    = (const float*)d_in[0];
    const float* pred   = (const float*)d_in[1];
    const int*   bids   = (const int*)d_in[2];
    const int*   target = (const int*)d_in[3];
    float* out = (float*)d_out;
    int n = in_sizes[1];  // pred_f element count = N

    unsigned* ws      = (unsigned*)d_ws;
    unsigned* hist    = ws + HIST_OFF;    // [4][8][256]
    unsigned* remk    = ws + REMK_OFF;
    unsigned* prefix  = ws + PREFIX_OFF;
    unsigned* active  = ws + ACTIVE_OFF;
    float*    thresh  = (float*)(ws + THRESH_OFF);

    // Only the histograms need zeroing; remk/prefix/active/thresh are fully
    // written by scan pass 0 before any later use.
    hipMemsetAsync(hist, 0, 4 * BATCHES * 256 * sizeof(unsigned), stream);

    // Pass 0
    hist0_kernel<<<1024, 256, 0, stream>>>(pred, bids, hist, n);
    scan_kernel<<<BATCHES, 256, 0, stream>>>(hist, target, remk, prefix, active,
                                             thresh, 0);

    // Passes 1..3
    for (int p = 1; p <= 3; p++) {
        unsigned* hp = hist + p * BATCHES * 256;
        int shiftHi = 32 - 8 * p;   // 24, 16, 8
        int shiftBin = 24 - 8 * p;  // 16, 8, 0
        histN_kernel<<<2048, 256, 0, stream>>>(pred, bids, prefix, active, hp, n,
                                               shiftHi, shiftBin);
        scan_kernel<<<BATCHES, 256, 0, stream>>>(hist, target, remk, prefix, active,
                                                 thresh, p);
    }

    // Prune + keep output (grid-stride, ~16 float4 iters/thread)
    prune_kernel<<<8192, 256, 0, stream>>>(fea, pred, bids, thresh, out, n);
}